// Round 1
// baseline (222.679 us; speedup 1.0000x reference)
//
#include <hip/hip_runtime.h>

#define BATCH 16

// ---------------------------------------------------------------------------
// Quad-lane primitives: all cross-lane traffic via DPP quad_perm (VALU pipe,
// no LDS/DS usage at all).
// ---------------------------------------------------------------------------
template <int CTRL>
__device__ __forceinline__ float qperm(float x) {
  int xi = __float_as_int(x);
  return __int_as_float(__builtin_amdgcn_update_dpp(xi, xi, CTRL, 0xF, 0xF, true));
}
// broadcast lane L of quad: CTRL = L*0x55 ; xor1 = 0xB1 ; xor2 = 0x4E

__device__ __forceinline__ float4 f4fma(float s, float4 a, float4 c) {
  c.x = fmaf(s, a.x, c.x);
  c.y = fmaf(s, a.y, c.y);
  c.z = fmaf(s, a.z, c.z);
  c.w = fmaf(s, a.w, c.w);
  return c;
}

// D=16 MPS chain (4 steps), vec distributed 4 components per quad lane.
// A layout: [s][f][16][16] floats. Per (s,i): 2 float4 loads per lane,
// 1 DPP broadcast, 8 fma.
__device__ __forceinline__ void mps16_chain(const float* __restrict__ A,
                                            int jq, const float tt[4],
                                            float vec[4]) {
#pragma unroll
  for (int s = 0; s < 4; s++) {
    const float4* A0v = (const float4*)(A + s * 512) + jq;
    const float4* A1v = A0v + 64;  // f=1 block (+256 floats)
    float4 q0 = {0.f, 0.f, 0.f, 0.f}, q1 = {0.f, 0.f, 0.f, 0.f};
#define ISTEP(i)                                         \
  {                                                      \
    float sv = qperm<(((i) >> 2) * 0x55)>(vec[(i) & 3]); \
    q0 = f4fma(sv, A0v[(i) * 4], q0);                    \
    q1 = f4fma(sv, A1v[(i) * 4], q1);                    \
  }
    ISTEP(0) ISTEP(1) ISTEP(2) ISTEP(3)
    ISTEP(4) ISTEP(5) ISTEP(6) ISTEP(7)
    ISTEP(8) ISTEP(9) ISTEP(10) ISTEP(11)
    ISTEP(12) ISTEP(13) ISTEP(14) ISTEP(15)
#undef ISTEP
    float ph = tt[s], om = 1.0f - ph;
    vec[0] = ph * q0.x + om * q1.x;
    vec[1] = ph * q0.y + om * q1.y;
    vec[2] = ph * q0.z + om * q1.z;
    vec[3] = ph * q0.w + om * q1.w;
  }
}

// ---------------------------------------------------------------------------
// 4-lane fused d+i unit. Lane jq (0..3) owns cell sg=jq of i-patch p; it
// recomputes the needed d output fully serially in-lane (D=4, float4 rows,
// only output component sd), then the quad runs the D=16 i-MPS.
// XS: x element stride (1 = b-major image, 16 = [cell][b] transposed).
// ---------------------------------------------------------------------------
template <int H, int XS>
__device__ __forceinline__ float fused_di_quad(
    const float* __restrict__ xb, int p, int jq,
    const float* __restrict__ dA, const float* __restrict__ dv,
    const float* __restrict__ dw,
    const float* __restrict__ iA, const float* __restrict__ iv,
    const float* __restrict__ iw) {
  constexpr int NH = (H - 2) / 2;
  constexpr int W2 = H / 2;
  int pi = p / W2, pj = p % W2;
  int r = 2 * pi + (jq >> 1), c = 2 * pj + (jq & 1);
  float tcell;
  bool border = (r == 0) | (r == H - 1) | (c == 0) | (c == H - 1);
  if (border) {
    tcell = xb[(r * H + c) * XS];  // d leaves borders untouched
  } else {
    int dpi = (r - 1) >> 1, dpj = (c - 1) >> 1;
    int sd = ((r - 1) & 1) * 2 + ((c - 1) & 1);
    int dp = dpi * NH + dpj;
    int R0 = 1 + 2 * dpi, C0 = 1 + 2 * dpj;
    float tins[4];
    tins[0] = xb[(R0 * H + C0) * XS];
    tins[1] = xb[(R0 * H + C0 + 1) * XS];
    tins[2] = xb[((R0 + 1) * H + C0) * XS];
    tins[3] = xb[((R0 + 1) * H + C0 + 1) * XS];
    const float4* Av = (const float4*)(dA + dp * 128);  // [s][f][4][4]
    float4 dvv = *(const float4*)(dv + dp * 4);
    float v0 = dvv.x, v1 = dvv.y, v2 = dvv.z, v3 = dvv.w;
#pragma unroll
    for (int s = 0; s < 4; s++) {
      const float4* A0 = Av + s * 8;
      float4 q0 = {0.f, 0.f, 0.f, 0.f}, q1 = {0.f, 0.f, 0.f, 0.f};
      q0 = f4fma(v0, A0[0], q0);
      q0 = f4fma(v1, A0[1], q0);
      q0 = f4fma(v2, A0[2], q0);
      q0 = f4fma(v3, A0[3], q0);
      q1 = f4fma(v0, A0[4], q1);
      q1 = f4fma(v1, A0[5], q1);
      q1 = f4fma(v2, A0[6], q1);
      q1 = f4fma(v3, A0[7], q1);
      float ph = tins[s], om = 1.0f - ph;
      v0 = ph * q0.x + om * q1.x;
      v1 = ph * q0.y + om * q1.y;
      v2 = ph * q0.z + om * q1.z;
      v3 = ph * q0.w + om * q1.w;
    }
    const float* wp = dw + dp * 16 + sd;  // only the component this cell needs
    float y = v0 * wp[0];
    y = fmaf(v1, wp[4], y);
    y = fmaf(v2, wp[8], y);
    y = fmaf(v3, wp[12], y);
    tcell = fmaxf(y, 0.0f);
  }
  // quad-broadcast the 4 cell values (VALU DPP, no DS)
  float tt[4];
  tt[0] = qperm<0x00>(tcell);
  tt[1] = qperm<0x55>(tcell);
  tt[2] = qperm<0xAA>(tcell);
  tt[3] = qperm<0xFF>(tcell);
  // i-MPS, D=16, vec components 4*jq .. 4*jq+3 in this lane
  float4 vv = *(const float4*)(iv + p * 16 + 4 * jq);
  float vec[4] = {vv.x, vv.y, vv.z, vv.w};
  mps16_chain(iA + (size_t)p * 2048, jq, tt, vec);
  float4 wv = *(const float4*)(iw + p * 16 + 4 * jq);
  float partial = vec[0] * wv.x;
  partial = fmaf(vec[1], wv.y, partial);
  partial = fmaf(vec[2], wv.z, partial);
  partial = fmaf(vec[3], wv.w, partial);
  partial += qperm<0xB1>(partial);  // xor 1
  partial += qperm<0x4E>(partial);  // xor 2
  return fmaxf(partial, 0.0f);
}

// ---------------------------------------------------------------------------
// One fused level. Wave (64 lanes) = 16 b x 4 jq for ONE patch p, so all A
// loads are quad-broadcast-coalesced. BP patches per block.
// Output hn is [p][b]-major (coalesced 64B writes; XS=16 reads next level).
// ---------------------------------------------------------------------------
template <int H, int BP, int XS>
__global__ __launch_bounds__(256) void level_kernel(
    const float* __restrict__ xin, float* __restrict__ hn,
    const float* __restrict__ dA, const float* __restrict__ dv,
    const float* __restrict__ dw, const float* __restrict__ iA,
    const float* __restrict__ iv, const float* __restrict__ iw) {
  int tid = threadIdx.x;
  int jq = tid & 3;
  int b = (tid >> 2) & 15;
  int p = blockIdx.x * BP + (tid >> 6);
  const float* xb = (XS == 1) ? (xin + b * H * H) : (xin + b);
  float o = fused_di_quad<H, XS>(xb, p, jq, dA, dv, dw, iA, iv, iw);
  if (jq == 0) hn[p * 16 + b] = o;  // 16 consecutive b -> one 64B segment
}

// ---------------------------------------------------------------------------
// Tail: levels 4,5,6 + final head. One block (256 thr) per batch element;
// level 4 is exactly 64 units x 4 lanes = 256 threads in the quad scheme.
// ---------------------------------------------------------------------------
struct TailArgs {
  const float* h3;      // [256 p][16 b]
  const float* in[21];  // d4A..fw  (d_in[19..39])
  float* out;
};

__global__ __launch_bounds__(256) void tail_kernel(TailArgs a) {
  __shared__ float x4[256];  // 16x16
  __shared__ float x5[64];   // 8x8
  __shared__ float x6[16];   // 4x4
  __shared__ float h6[4];    // 2x2
  int b = blockIdx.x;
  int tid = threadIdx.x;
  x4[tid] = a.h3[tid * 16 + b];
  __syncthreads();
  // level 4: H=16 -> 64 units x 4 lanes = 256 threads
  {
    int jq = tid & 3, p = tid >> 2;
    float o = fused_di_quad<16, 1>(x4, p, jq, a.in[0], a.in[1], a.in[2],
                                   a.in[3], a.in[4], a.in[5]);
    if (jq == 0) x5[p] = o;
  }
  __syncthreads();
  // level 5: H=8 -> 16 units -> 64 threads
  if (tid < 64) {
    int jq = tid & 3, p = tid >> 2;
    float o = fused_di_quad<8, 1>(x5, p, jq, a.in[6], a.in[7], a.in[8],
                                  a.in[9], a.in[10], a.in[11]);
    if (jq == 0) x6[p] = o;
  }
  __syncthreads();
  // level 6: H=4 -> 4 units -> 16 threads
  if (tid < 16) {
    int jq = tid & 3, p = tid >> 2;
    float o = fused_di_quad<4, 1>(x6, p, jq, a.in[12], a.in[13], a.in[14],
                                  a.in[15], a.in[16], a.in[17]);
    if (jq == 0) h6[p] = o;
  }
  __syncthreads();
  // final head: flat (2x2) -> 10 classes; one quad
  if (tid < 4) {
    int jq = tid;
    const float* fA = a.in[18];
    const float* fv = a.in[19];
    const float* fw = a.in[20];
    float tt[4] = {h6[0], h6[1], h6[2], h6[3]};
    float4 vv = *(const float4*)(fv + 4 * jq);
    float vec[4] = {vv.x, vv.y, vv.z, vv.w};
    mps16_chain(fA, jq, tt, vec);
    float acc[10];
#pragma unroll
    for (int o = 0; o < 10; o++) acc[o] = 0.f;
#pragma unroll
    for (int k = 0; k < 4; k++)
#pragma unroll
      for (int o = 0; o < 10; o++)
        acc[o] = fmaf(vec[k], fw[(4 * jq + k) * 10 + o], acc[o]);
#pragma unroll
    for (int o = 0; o < 10; o++) {
      acc[o] += qperm<0xB1>(acc[o]);
      acc[o] += qperm<0x4E>(acc[o]);
    }
    if (jq == 0) {
#pragma unroll
      for (int o = 0; o < 10; o++) a.out[b * 10 + o] = fmaxf(acc[o], 0.0f);
    }
  }
}

extern "C" void kernel_launch(void* const* d_in, const int* in_sizes, int n_in,
                              void* d_out, int out_size, void* d_ws, size_t ws_size,
                              hipStream_t stream) {
  const float* x = (const float*)d_in[0];
  float* ws = (float*)d_ws;
  float* h1 = ws;           // 4096 p x 16 b = 65536
  float* h2 = h1 + 65536;   // 1024 p x 16 b = 16384
  float* h3 = h2 + 16384;   //  256 p x 16 b =  4096

  // level 1: H=128, 4096 patches, x is b-major
  level_kernel<128, 4, 1><<<1024, 256, 0, stream>>>(
      x, h1, (const float*)d_in[1], (const float*)d_in[2],
      (const float*)d_in[3], (const float*)d_in[4], (const float*)d_in[5],
      (const float*)d_in[6]);
  // level 2: H=64, 1024 patches, input [cell][b]
  level_kernel<64, 4, 16><<<256, 256, 0, stream>>>(
      h1, h2, (const float*)d_in[7], (const float*)d_in[8],
      (const float*)d_in[9], (const float*)d_in[10], (const float*)d_in[11],
      (const float*)d_in[12]);
  // level 3: H=32, 256 patches, 1 wave per patch spread across CUs
  level_kernel<32, 1, 16><<<256, 64, 0, stream>>>(
      h2, h3, (const float*)d_in[13], (const float*)d_in[14],
      (const float*)d_in[15], (const float*)d_in[16], (const float*)d_in[17],
      (const float*)d_in[18]);

  TailArgs ta;
  ta.h3 = h3;
  for (int i = 0; i < 21; i++) ta.in[i] = (const float*)d_in[19 + i];
  ta.out = (float*)d_out;
  tail_kernel<<<BATCH, 256, 0, stream>>>(ta);
}

// Round 2
// 195.533 us; speedup vs baseline: 1.1388x; 1.1388x over previous
//
#include <hip/hip_runtime.h>

#define BATCH 16

// ---------------------------------------------------------------------------
// Quad-lane primitives: all cross-lane traffic via DPP quad_perm (VALU pipe).
// ---------------------------------------------------------------------------
template <int CTRL>
__device__ __forceinline__ float qperm(float x) {
  int xi = __float_as_int(x);
  return __int_as_float(__builtin_amdgcn_update_dpp(xi, xi, CTRL, 0xF, 0xF, true));
}

__device__ __forceinline__ float4 f4fma(float s, float4 a, float4 c) {
  c.x = fmaf(s, a.x, c.x);
  c.y = fmaf(s, a.y, c.y);
  c.z = fmaf(s, a.z, c.z);
  c.w = fmaf(s, a.w, c.w);
  return c;
}

// D=16 MPS chain (4 steps), vec distributed 4 components per quad lane.
// A layout: [s][f][16][16] floats (works for global or LDS pointers; always
// inlined so the compiler sees the address space).
__device__ __forceinline__ void mps16_chain(const float* A, int jq,
                                            const float tt[4], float vec[4]) {
#pragma unroll
  for (int s = 0; s < 4; s++) {
    const float4* A0v = (const float4*)(A + s * 512) + jq;
    const float4* A1v = A0v + 64;  // f=1 block (+256 floats)
    float4 q0 = {0.f, 0.f, 0.f, 0.f}, q1 = {0.f, 0.f, 0.f, 0.f};
#define ISTEP(i)                                         \
  {                                                      \
    float sv = qperm<(((i) >> 2) * 0x55)>(vec[(i) & 3]); \
    q0 = f4fma(sv, A0v[(i) * 4], q0);                    \
    q1 = f4fma(sv, A1v[(i) * 4], q1);                    \
  }
    ISTEP(0) ISTEP(1) ISTEP(2) ISTEP(3)
    ISTEP(4) ISTEP(5) ISTEP(6) ISTEP(7)
    ISTEP(8) ISTEP(9) ISTEP(10) ISTEP(11)
    ISTEP(12) ISTEP(13) ISTEP(14) ISTEP(15)
#undef ISTEP
    float ph = tt[s], om = 1.0f - ph;
    vec[0] = ph * q0.x + om * q1.x;
    vec[1] = ph * q0.y + om * q1.y;
    vec[2] = ph * q0.z + om * q1.z;
    vec[3] = ph * q0.w + om * q1.w;
  }
}

// ---------------------------------------------------------------------------
// Global-memory 4-lane fused d+i unit (used by the tiny tail levels where
// params are L2-resident). XS: x element stride (1 = dense, 16 = [cell][b]).
// ---------------------------------------------------------------------------
template <int H, int XS>
__device__ __forceinline__ float fused_di_quad(
    const float* __restrict__ xb, int p, int jq,
    const float* __restrict__ dA, const float* __restrict__ dv,
    const float* __restrict__ dw,
    const float* __restrict__ iA, const float* __restrict__ iv,
    const float* __restrict__ iw) {
  constexpr int NH = (H - 2) / 2;
  constexpr int W2 = H / 2;
  int pi = p / W2, pj = p % W2;
  int r = 2 * pi + (jq >> 1), c = 2 * pj + (jq & 1);
  float tcell;
  bool border = (r == 0) | (r == H - 1) | (c == 0) | (c == H - 1);
  if (border) {
    tcell = xb[(r * H + c) * XS];
  } else {
    int dpi = (r - 1) >> 1, dpj = (c - 1) >> 1;
    int sd = ((r - 1) & 1) * 2 + ((c - 1) & 1);
    int dp = dpi * NH + dpj;
    int R0 = 1 + 2 * dpi, C0 = 1 + 2 * dpj;
    float tins[4];
    tins[0] = xb[(R0 * H + C0) * XS];
    tins[1] = xb[(R0 * H + C0 + 1) * XS];
    tins[2] = xb[((R0 + 1) * H + C0) * XS];
    tins[3] = xb[((R0 + 1) * H + C0 + 1) * XS];
    const float4* Av = (const float4*)(dA + dp * 128);  // [s][f][4][4]
    float4 dvv = *(const float4*)(dv + dp * 4);
    float v0 = dvv.x, v1 = dvv.y, v2 = dvv.z, v3 = dvv.w;
#pragma unroll
    for (int s = 0; s < 4; s++) {
      const float4* A0 = Av + s * 8;
      float4 q0 = {0.f, 0.f, 0.f, 0.f}, q1 = {0.f, 0.f, 0.f, 0.f};
      q0 = f4fma(v0, A0[0], q0);
      q0 = f4fma(v1, A0[1], q0);
      q0 = f4fma(v2, A0[2], q0);
      q0 = f4fma(v3, A0[3], q0);
      q1 = f4fma(v0, A0[4], q1);
      q1 = f4fma(v1, A0[5], q1);
      q1 = f4fma(v2, A0[6], q1);
      q1 = f4fma(v3, A0[7], q1);
      float ph = tins[s], om = 1.0f - ph;
      v0 = ph * q0.x + om * q1.x;
      v1 = ph * q0.y + om * q1.y;
      v2 = ph * q0.z + om * q1.z;
      v3 = ph * q0.w + om * q1.w;
    }
    const float* wp = dw + dp * 16 + sd;
    float y = v0 * wp[0];
    y = fmaf(v1, wp[4], y);
    y = fmaf(v2, wp[8], y);
    y = fmaf(v3, wp[12], y);
    tcell = fmaxf(y, 0.0f);
  }
  float tt[4];
  tt[0] = qperm<0x00>(tcell);
  tt[1] = qperm<0x55>(tcell);
  tt[2] = qperm<0xAA>(tcell);
  tt[3] = qperm<0xFF>(tcell);
  float4 vv = *(const float4*)(iv + p * 16 + 4 * jq);
  float vec[4] = {vv.x, vv.y, vv.z, vv.w};
  mps16_chain(iA + (size_t)p * 2048, jq, tt, vec);
  float4 wv = *(const float4*)(iw + p * 16 + 4 * jq);
  float partial = vec[0] * wv.x;
  partial = fmaf(vec[1], wv.y, partial);
  partial = fmaf(vec[2], wv.z, partial);
  partial = fmaf(vec[3], wv.w, partial);
  partial += qperm<0xB1>(partial);  // xor 1
  partial += qperm<0x4E>(partial);  // xor 2
  return fmaxf(partial, 0.0f);
}

// ---------------------------------------------------------------------------
// Staged level kernel. Block = 256 thr = 4 waves = 4 consecutive patches of
// one patch-row. Stage phase: cooperatively reg-stage all params for the 4
// patches into LDS (streaming, 256 threads x ~14 float4 in flight). Compute
// phase: quad-lane fused d+i with A from LDS. x reads are issued pre-barrier.
// Input x layout: [cell][b] (b contiguous, 16 floats). Output: [p][b].
// ---------------------------------------------------------------------------
#define OFF_IA 0      // 4 x 2048
#define OFF_IV 8192   // 4 x 16
#define OFF_IW 8256   // 4 x 16
#define OFF_DA 8320   // 10 slots x 132 (128 + 4 pad -> bank spread)
#define OFF_DV 9640   // 10 x 4
#define OFF_DW 9680   // 10 x 16
#define LDS_TOT 9840  // floats = 39360 B -> 4 blocks/CU

template <int H>
__global__ __launch_bounds__(256) void level_kernel(
    const float* __restrict__ xT, float* __restrict__ hn,
    const float* __restrict__ dA, const float* __restrict__ dv,
    const float* __restrict__ dw, const float* __restrict__ iA,
    const float* __restrict__ iv, const float* __restrict__ iw) {
  constexpr int W2 = H / 2, NH = (H - 2) / 2;
  __shared__ __align__(16) float lds[LDS_TOT];
  float4* l4 = (float4*)lds;
  const int tid = threadIdx.x;
  const int p0 = blockIdx.x * 4;
  const int pi = p0 / W2, pj0 = p0 % W2;
  const int jq = tid & 3, b = (tid >> 2) & 15, w = tid >> 6;
  const int pj = pj0 + w;
  const int r = 2 * pi + (jq >> 1), c = 2 * pj + (jq & 1);
  const bool border = (r == 0) | (r == H - 1) | (c == 0) | (c == H - 1);
  const int dpi = (r - 1) >> 1, dpj = (c - 1) >> 1;

  // ---- pre-load x values (independent of LDS; latency hides under staging)
  float xv0, xv1, xv2, xv3;
  if (border) {
    xv0 = xT[(r * H + c) * 16 + b];
  } else {
    int R0 = 1 + 2 * dpi, C0 = 1 + 2 * dpj;
    xv0 = xT[(R0 * H + C0) * 16 + b];
    xv1 = xT[(R0 * H + C0 + 1) * 16 + b];
    xv2 = xT[((R0 + 1) * H + C0) * 16 + b];
    xv3 = xT[((R0 + 1) * H + C0 + 1) * 16 + b];
  }

  // ---- stage phase -------------------------------------------------------
  {
    const float4* iA4 = (const float4*)iA + p0 * 512;
    float4 ra[8];
#pragma unroll
    for (int k = 0; k < 8; k++) ra[k] = iA4[tid + k * 256];

    // dA: 2 rows x 5 cols x 32 granules = 320
    float4 rd0, rd1;
    int sl0, gr0, sl1, gr1;
    const bool md1 = tid < 64;
    {
      int g = tid;
      int rs = g / 160, rem = g % 160, cs = rem / 32;
      gr0 = rem % 32;
      int di = min(max(pi - 1 + rs, 0), NH - 1);
      int dj = min(max(pj0 - 1 + cs, 0), NH - 1);
      sl0 = rs * 5 + cs;
      rd0 = *((const float4*)dA + (di * NH + dj) * 32 + gr0);
    }
    if (md1) {
      int g = tid + 256;
      int rs = g / 160, rem = g % 160, cs = rem / 32;
      gr1 = rem % 32;
      int di = min(max(pi - 1 + rs, 0), NH - 1);
      int dj = min(max(pj0 - 1 + cs, 0), NH - 1);
      sl1 = rs * 5 + cs;
      rd1 = *((const float4*)dA + (di * NH + dj) * 32 + gr1);
    }
    // dv: 10 granules
    float4 rv;
    const bool mv = tid < 10;
    if (mv) {
      int rs = tid / 5, cs = tid % 5;
      int di = min(max(pi - 1 + rs, 0), NH - 1);
      int dj = min(max(pj0 - 1 + cs, 0), NH - 1);
      rv = *((const float4*)dv + (di * NH + dj));
    }
    // dw: 40 granules
    float4 rw;
    const bool mw = tid < 40;
    if (mw) {
      int rs = tid / 20, rem = tid % 20, cs = rem / 4, gr = rem % 4;
      int di = min(max(pi - 1 + rs, 0), NH - 1);
      int dj = min(max(pj0 - 1 + cs, 0), NH - 1);
      rw = *((const float4*)dw + (di * NH + dj) * 4 + gr);
    }
    // iv/iw: 16 granules each
    float4 rvv, rww;
    const bool mi = tid < 16;
    if (mi) {
      rvv = *((const float4*)iv + p0 * 4 + tid);
      rww = *((const float4*)iw + p0 * 4 + tid);
    }
    // writes
#pragma unroll
    for (int k = 0; k < 8; k++) l4[OFF_IA / 4 + tid + k * 256] = ra[k];
    l4[OFF_DA / 4 + sl0 * 33 + gr0] = rd0;
    if (md1) l4[OFF_DA / 4 + sl1 * 33 + gr1] = rd1;
    if (mv) l4[OFF_DV / 4 + tid] = rv;
    if (mw) l4[OFF_DW / 4 + tid] = rw;
    if (mi) l4[OFF_IV / 4 + tid] = rvv;
    if (mi) l4[OFF_IW / 4 + tid] = rww;
  }
  __syncthreads();

  // ---- compute phase -----------------------------------------------------
  float tcell;
  if (border) {
    tcell = xv0;
  } else {
    int sd = ((r - 1) & 1) * 2 + ((c - 1) & 1);
    int slot = (dpi - pi + 1) * 5 + (dpj - pj0 + 1);
    const float4* Av = (const float4*)(lds + OFF_DA + slot * 132);
    float4 dvv = *(const float4*)(lds + OFF_DV + slot * 4);
    float v0 = dvv.x, v1 = dvv.y, v2 = dvv.z, v3 = dvv.w;
    float tins[4] = {xv0, xv1, xv2, xv3};
#pragma unroll
    for (int s = 0; s < 4; s++) {
      const float4* A0 = Av + s * 8;
      float4 q0 = {0.f, 0.f, 0.f, 0.f}, q1 = {0.f, 0.f, 0.f, 0.f};
      q0 = f4fma(v0, A0[0], q0);
      q0 = f4fma(v1, A0[1], q0);
      q0 = f4fma(v2, A0[2], q0);
      q0 = f4fma(v3, A0[3], q0);
      q1 = f4fma(v0, A0[4], q1);
      q1 = f4fma(v1, A0[5], q1);
      q1 = f4fma(v2, A0[6], q1);
      q1 = f4fma(v3, A0[7], q1);
      float ph = tins[s], om = 1.0f - ph;
      v0 = ph * q0.x + om * q1.x;
      v1 = ph * q0.y + om * q1.y;
      v2 = ph * q0.z + om * q1.z;
      v3 = ph * q0.w + om * q1.w;
    }
    const float* wp = lds + OFF_DW + slot * 16 + sd;
    float y = v0 * wp[0];
    y = fmaf(v1, wp[4], y);
    y = fmaf(v2, wp[8], y);
    y = fmaf(v3, wp[12], y);
    tcell = fmaxf(y, 0.0f);
  }
  float tt[4];
  tt[0] = qperm<0x00>(tcell);
  tt[1] = qperm<0x55>(tcell);
  tt[2] = qperm<0xAA>(tcell);
  tt[3] = qperm<0xFF>(tcell);
  float4 vv = *(const float4*)(lds + OFF_IV + w * 16 + 4 * jq);
  float vec[4] = {vv.x, vv.y, vv.z, vv.w};
  mps16_chain(lds + OFF_IA + w * 2048, jq, tt, vec);
  float4 wv = *(const float4*)(lds + OFF_IW + w * 16 + 4 * jq);
  float partial = vec[0] * wv.x;
  partial = fmaf(vec[1], wv.y, partial);
  partial = fmaf(vec[2], wv.z, partial);
  partial = fmaf(vec[3], wv.w, partial);
  partial += qperm<0xB1>(partial);
  partial += qperm<0x4E>(partial);
  if (jq == 0) hn[(p0 + w) * 16 + b] = fmaxf(partial, 0.0f);
}

// ---------------------------------------------------------------------------
// x transpose: [b][16384] -> [cell][b] so all level-kernel x reads coalesce.
// ---------------------------------------------------------------------------
__global__ __launch_bounds__(256) void transpose_kernel(
    const float* __restrict__ x, float* __restrict__ xT) {
  __shared__ float t[64][17];
  int tid = threadIdx.x;
  int c0 = blockIdx.x * 64;
  {
    int bb = tid >> 4, c4 = tid & 15;
    float4 v = *((const float4*)(x + bb * 16384 + c0) + c4);
    t[c4 * 4 + 0][bb] = v.x;
    t[c4 * 4 + 1][bb] = v.y;
    t[c4 * 4 + 2][bb] = v.z;
    t[c4 * 4 + 3][bb] = v.w;
  }
  __syncthreads();
  {
    int cl = tid >> 2, bq = tid & 3;
    float4 v;
    v.x = t[cl][bq * 4 + 0];
    v.y = t[cl][bq * 4 + 1];
    v.z = t[cl][bq * 4 + 2];
    v.w = t[cl][bq * 4 + 3];
    *((float4*)(xT + (c0 + cl) * 16) + bq) = v;
  }
}

// ---------------------------------------------------------------------------
// Tail: levels 5,6 + head. 4 blocks x 256 thr; block covers 4 batch elems.
// Full lane occupancy per phase: L5 4b x 16p x 4jq = 256; L6 4b x 4p x 4jq =
// 64; head 4b x 4jq = 16. Params stay warm in L1/L2 (~170 KB, 4 CUs).
// ---------------------------------------------------------------------------
struct TailArgs {
  const float* h4;      // [64 cell][16 b]
  const float* in[15];  // d5A..fw  (d_in[25..39])
  float* out;
};

__global__ __launch_bounds__(256) void tail2_kernel(TailArgs a) {
  __shared__ float h5l[4][16];
  __shared__ float h6l[4][4];
  int tid = threadIdx.x;
  // level 5: H=8, input h4 [cell][b]
  {
    int jq = tid & 3, p = (tid >> 2) & 15, bl = tid >> 6;
    int b = blockIdx.x * 4 + bl;
    float o = fused_di_quad<8, 16>(a.h4 + b, p, jq, a.in[0], a.in[1], a.in[2],
                                   a.in[3], a.in[4], a.in[5]);
    if (jq == 0) h5l[bl][p] = o;
  }
  __syncthreads();
  // level 6: H=4, input h5l[bl] (dense 4x4)
  if (tid < 64) {
    int jq = tid & 3, p = (tid >> 2) & 3, bl = tid >> 4;
    float o = fused_di_quad<4, 1>(&h5l[bl][0], p, jq, a.in[6], a.in[7],
                                  a.in[8], a.in[9], a.in[10], a.in[11]);
    if (jq == 0) h6l[bl][p] = o;
  }
  __syncthreads();
  // final head: flat (2x2) -> 10 classes; one quad per b
  if (tid < 16) {
    int jq = tid & 3, bl = tid >> 2;
    const float* fA = a.in[12];
    const float* fv = a.in[13];
    const float* fw = a.in[14];
    float tt[4] = {h6l[bl][0], h6l[bl][1], h6l[bl][2], h6l[bl][3]};
    float4 vv = *(const float4*)(fv + 4 * jq);
    float vec[4] = {vv.x, vv.y, vv.z, vv.w};
    mps16_chain(fA, jq, tt, vec);
    float acc[10];
#pragma unroll
    for (int o = 0; o < 10; o++) acc[o] = 0.f;
#pragma unroll
    for (int k = 0; k < 4; k++)
#pragma unroll
      for (int o = 0; o < 10; o++)
        acc[o] = fmaf(vec[k], fw[(4 * jq + k) * 10 + o], acc[o]);
#pragma unroll
    for (int o = 0; o < 10; o++) {
      acc[o] += qperm<0xB1>(acc[o]);
      acc[o] += qperm<0x4E>(acc[o]);
    }
    if (jq == 0) {
      int b = blockIdx.x * 4 + bl;
#pragma unroll
      for (int o = 0; o < 10; o++) a.out[b * 10 + o] = fmaxf(acc[o], 0.0f);
    }
  }
}

extern "C" void kernel_launch(void* const* d_in, const int* in_sizes, int n_in,
                              void* d_out, int out_size, void* d_ws, size_t ws_size,
                              hipStream_t stream) {
  const float* x = (const float*)d_in[0];
  float* ws = (float*)d_ws;
  float* xT = ws;             // 16384 cells x 16 b = 262144
  float* h1 = xT + 262144;    // 4096 x 16
  float* h2 = h1 + 65536;     // 1024 x 16
  float* h3 = h2 + 16384;     //  256 x 16
  float* h4 = h3 + 4096;      //   64 x 16

  transpose_kernel<<<256, 256, 0, stream>>>(x, xT);
  // level 1: H=128, 4096 patches -> 1024 blocks
  level_kernel<128><<<1024, 256, 0, stream>>>(
      xT, h1, (const float*)d_in[1], (const float*)d_in[2],
      (const float*)d_in[3], (const float*)d_in[4], (const float*)d_in[5],
      (const float*)d_in[6]);
  // level 2: H=64, 1024 patches -> 256 blocks
  level_kernel<64><<<256, 256, 0, stream>>>(
      h1, h2, (const float*)d_in[7], (const float*)d_in[8],
      (const float*)d_in[9], (const float*)d_in[10], (const float*)d_in[11],
      (const float*)d_in[12]);
  // level 3: H=32, 256 patches -> 64 blocks
  level_kernel<32><<<64, 256, 0, stream>>>(
      h2, h3, (const float*)d_in[13], (const float*)d_in[14],
      (const float*)d_in[15], (const float*)d_in[16], (const float*)d_in[17],
      (const float*)d_in[18]);
  // level 4: H=16, 64 patches -> 16 blocks
  level_kernel<16><<<16, 256, 0, stream>>>(
      h3, h4, (const float*)d_in[19], (const float*)d_in[20],
      (const float*)d_in[21], (const float*)d_in[22], (const float*)d_in[23],
      (const float*)d_in[24]);

  TailArgs ta;
  ta.h4 = h4;
  for (int i = 0; i < 15; i++) ta.in[i] = (const float*)d_in[25 + i];
  ta.out = (float*)d_out;
  tail2_kernel<<<4, 256, 0, stream>>>(ta);
}